// Round 1
// baseline (316.922 us; speedup 1.0000x reference)
//
#include <hip/hip_runtime.h>

// out[n,c,j,i] = x[n, c, clamp(j + sy - 4, 0, 127), clamp(i + sx - 4, 0, 127)]
// where (sx, sy) = shift[n]. Pure memory-bound shifted copy.

constexpr int Himg = 128;   // height = width = 128
constexpr int Cimg = 12;    // channels
constexpr int PADc = 4;     // PADDING

__global__ __launch_bounds__(256) void random_shift_kernel(
    const float* __restrict__ x,
    const int* __restrict__ shift,
    float* __restrict__ out)
{
    // grid: (Cimg*Himg*Himg/4/256, N) = (192, 256)
    const int n     = blockIdx.y;
    const int flat4 = blockIdx.x * 256 + threadIdx.x;   // [0, 12*128*32)
    const int col4  = flat4 & 31;                        // which float4 in row
    const int rowi  = flat4 >> 5;                        // [0, 12*128)
    const int j     = rowi & (Himg - 1);                 // row within image
    const int cc    = rowi >> 7;                         // channel

    // per-image shift (uniform across the block -> scalar loads)
    const int sx = shift[2 * n];
    const int sy = shift[2 * n + 1];
    const int dx = sx - PADc;   // in [-4, 4]
    const int dy = sy - PADc;

    int sj = j + dy;
    sj = sj < 0 ? 0 : (sj > Himg - 1 ? Himg - 1 : sj);

    const long long img_base = (long long)(n * Cimg + cc) * (Himg * Himg);
    const float* __restrict__ src_row = x + img_base + (long long)sj * Himg;
    float* __restrict__ dst = out + img_base + (long long)j * Himg + col4 * 4;

    const int i0 = col4 * 4 + dx;   // leftmost source column for this float4
    float4 v;
    if (i0 >= 0 && i0 + 3 <= Himg - 1) {
        // fully interior: one (possibly unaligned-by-dx*4B) vector load
        v = *reinterpret_cast<const float4*>(src_row + i0);
    } else {
        // row edge: clamp each of the 4 source columns
        int a = i0, b = i0 + 1, c2 = i0 + 2, d = i0 + 3;
        a  = a  < 0 ? 0 : (a  > Himg - 1 ? Himg - 1 : a);
        b  = b  < 0 ? 0 : (b  > Himg - 1 ? Himg - 1 : b);
        c2 = c2 < 0 ? 0 : (c2 > Himg - 1 ? Himg - 1 : c2);
        d  = d  < 0 ? 0 : (d  > Himg - 1 ? Himg - 1 : d);
        v = make_float4(src_row[a], src_row[b], src_row[c2], src_row[d]);
    }
    *reinterpret_cast<float4*>(dst) = v;
}

extern "C" void kernel_launch(void* const* d_in, const int* in_sizes, int n_in,
                              void* d_out, int out_size, void* d_ws, size_t ws_size,
                              hipStream_t stream) {
    const float* x     = (const float*)d_in[0];
    const int*   shift = (const int*)d_in[1];
    float*       out   = (float*)d_out;

    const int N = 256;
    // per image: Cimg*Himg*Himg/4 float4s = 49152 -> 192 blocks of 256 threads
    dim3 grid(Cimg * Himg * (Himg / 4) / 256, N);
    random_shift_kernel<<<grid, 256, 0, stream>>>(x, shift, out);
}